// Round 3
// baseline (882.484 us; speedup 1.0000x reference)
//
#include <hip/hip_runtime.h>
#include <hip/hip_bf16.h>

// Problem constants
#define NEXP 8
#define KIN 2048
#define NOUT 2048
#define NTOK 32768

// GEMM tile (256^2, 8-phase schedule, 512 threads = 8 waves 2Mx4N)
#define BM 256
#define BN 256
#define BK 64

#define NBLK (NTOK / 256)              // 128 token blocks for rank
#define MAXTILE (NTOK / BM + NEXP - 1) // 135 worst-case M-tiles

typedef unsigned int u32;
typedef unsigned short u16;
typedef __bf16 bf16x8 __attribute__((ext_vector_type(8)));
typedef float f32x4 __attribute__((ext_vector_type(4)));

__device__ __forceinline__ u16 f2bf(float f) {
    u32 u = __float_as_uint(f);
    u += 0x7FFFu + ((u >> 16) & 1u);   // round-to-nearest-even; inputs are finite
    return (u16)(u >> 16);
}

__device__ __forceinline__ void load_lds16(const void* g, void* l) {
    __builtin_amdgcn_global_load_lds(
        (const __attribute__((address_space(1))) u32*)g,
        (__attribute__((address_space(3))) u32*)l, 16, 0, 0);
}

// Pass 1: per-block LDS histogram + per-token local rank.
__global__ void rank_k(const int* __restrict__ assign, int* __restrict__ counts,
                       int* __restrict__ rank, int* __restrict__ blockBase) {
    __shared__ int lc[NEXP];
    int t = blockIdx.x * 256 + threadIdx.x;
    if (threadIdx.x < NEXP) lc[threadIdx.x] = 0;
    __syncthreads();
    int e = assign[t];
    rank[t] = atomicAdd(&lc[e], 1);
    __syncthreads();
    if (threadIdx.x < NEXP)
        blockBase[blockIdx.x * NEXP + threadIdx.x] =
            atomicAdd(&counts[threadIdx.x], lc[threadIdx.x]);
}

// Pass 2: prefix + tile table + persistent-GEMM control.
// ctrl: counts[0..7], tokStart[8..16], [18]=total sids, [19]=steal counter.
__global__ void prefix_k(int* __restrict__ ctrl, int4* __restrict__ tileTable) {
    __shared__ int cnt[NEXP], ts[NEXP + 1], tstart[NEXP + 1];
    int t = threadIdx.x;
    if (t < NEXP) cnt[t] = ctrl[t];
    __syncthreads();
    if (t == 0) {
        int s = 0, tile = 0;
        for (int e = 0; e < NEXP; e++) {
            ts[e] = s; tstart[e] = tile;
            s += cnt[e]; tile += (cnt[e] + BM - 1) / BM;
        }
        ts[NEXP] = s; tstart[NEXP] = tile;
        for (int e = 0; e <= NEXP; e++) ctrl[8 + e] = ts[e];
        ctrl[18] = tile * 8;   // total work units (tile * 8 N-blocks)
        ctrl[19] = 256;        // steal counter: first 256 sids are static (bid)
    }
    __syncthreads();
    for (int tt = t; tt < MAXTILE; tt += blockDim.x) {
        int4 v = make_int4(0, 0, 0, 0);
#pragma unroll
        for (int e = 0; e < NEXP; e++) {
            if (tt >= tstart[e] && tt < tstart[e + 1]) {
                int i = tt - tstart[e];
                v = make_int4(ts[e] + i * BM, ts[e] + cnt[e], e, 0);
            }
        }
        tileTable[tt] = v;
    }
}

// Pass 3: fused scatter + A fp32->bf16 gather-convert. Writes A in
// expert-sorted (gathered) row order so GEMM A staging is contiguous,
// plus the token list for the output scatter. 8 tokens per 256-thr block.
__global__ void gather_k(const float* __restrict__ A, const int* __restrict__ assign,
                         const int* __restrict__ rank, const int* __restrict__ blockBase,
                         const int* __restrict__ ctrl, u16* __restrict__ Ag,
                         int* __restrict__ list) {
    int tid = threadIdx.x;
    int tok = blockIdx.x * 8 + (tid >> 5);
    int l = tid & 31;
    int e = assign[tok];
    int dst = ctrl[8 + e] + blockBase[(tok >> 8) * NEXP + e] + rank[tok];
    if (l == 0) list[dst] = tok;
    const float4* s = (const float4*)(A + (size_t)tok * KIN);
    uint4* d = (uint4*)(Ag + (size_t)dst * KIN);
#pragma unroll
    for (int it = 0; it < 8; ++it) {
        int q = it * 32 + l;               // uint4 index within row (256 total)
        float4 f0 = s[q * 2], f1 = s[q * 2 + 1];
        uint4 o;
        o.x = (u32)f2bf(f0.x) | ((u32)f2bf(f0.y) << 16);
        o.y = (u32)f2bf(f0.z) | ((u32)f2bf(f0.w) << 16);
        o.z = (u32)f2bf(f1.x) | ((u32)f2bf(f1.y) << 16);
        o.w = (u32)f2bf(f1.z) | ((u32)f2bf(f1.w) << 16);
        d[q] = o;
    }
}

// Streaming fp32 -> bf16 (vec8 per thread) for W.
__global__ void conv_k(const float* __restrict__ src, u16* __restrict__ dst) {
    size_t i = ((size_t)blockIdx.x * 256 + threadIdx.x) << 3;
    const float4* s = (const float4*)(src + i);
    float4 f0 = s[0], f1 = s[1];
    uint4 o;
    o.x = (u32)f2bf(f0.x) | ((u32)f2bf(f0.y) << 16);
    o.y = (u32)f2bf(f0.z) | ((u32)f2bf(f0.w) << 16);
    o.z = (u32)f2bf(f1.x) | ((u32)f2bf(f1.y) << 16);
    o.w = (u32)f2bf(f1.z) | ((u32)f2bf(f1.w) << 16);
    *(uint4*)(dst + i) = o;
}

// ---------------------------------------------------------------------------
// Persistent 256x256x64 8-wave grouped GEMM. Grid = 256 (1 block/CU, LDS-
// bound). Each block steals sids (tile-major: tile=sid>>3, nblk=sid&7) from
// ctrl[19]; during tile T's K31 MFMAs + epilogue stores it decodes T+1 and
// stages T+1's K0/K1 into the freed LDS buffers, so the loop-top vmcnt(0)
// costs only the last few epilogue stores -> prologue/epilogue bubbles are
// hidden. A is pre-gathered so staging addresses depend only on rowBase.
// LDS: buf b at b*65536 {A 32KB, B 32KB}, swizzle slot^=(row&7) as before;
// listLds @131072 (output scatter only); steal slot @132096.
// ---------------------------------------------------------------------------
#define BARS() asm volatile("s_barrier" ::: "memory")
#define WVM(N) asm volatile("s_waitcnt vmcnt(" #N ")" ::: "memory")
#define WLG0() asm volatile("s_waitcnt lgkmcnt(0)" ::: "memory")

__global__ __launch_bounds__(512, 2) void gemm_k(const u16* __restrict__ Ab,
                                                 const u16* __restrict__ Wb,
                                                 const int* __restrict__ list,
                                                 const int4* __restrict__ tileTable,
                                                 int* ctrl,
                                                 float* __restrict__ out) {
    extern __shared__ char sh[];
    int* listLds = (int*)(sh + 131072);
    volatile int* shsid = (volatile int*)(sh + 132096);

    int total = ctrl[18];
    int tid = threadIdx.x;
    int lane = tid & 63, w = tid >> 6;
    int wm = w >> 2, wn = w & 3;              // 2 x 4 wave grid

    // per-thread constants
    int srow = (w << 4) + (lane >> 3);                      // staging row in half
    u32 ksoB = (u32)((((lane & 7) ^ (lane >> 3)) << 4));    // inverse-swizzled k-slot
    u32 ldsOff = (u32)((w << 11) + (lane << 4));
    u32 s0 = (u32)((((lane >> 4) ^ (lane & 7)) << 4));      // read swizzle
    u32 aRow = (u32)((wm * 128 + (lane & 15)) * 128);
    u32 bRow = (u32)(32768 + (wn * 64 + (lane & 15)) * 128);

    // --- first sid: static assignment (counter pre-set to 256 by prefix_k) ---
    int sid = blockIdx.x;
    if (sid >= total) return;
    int4 tt = tileTable[sid >> 3];
    int cnt = tt.y - tt.x;
    int cb = (sid & 7) * BN + wn * 64 + (lane & 15);
    u32 aO = (u32)(tt.x + srow) * 4096u + ksoB;
    u32 bO = (u32)(tt.z * NOUT + (sid & 7) * BN + srow) * 4096u + ksoB;
    int vvn = 0;
    if (tid < 256) vvn = list[min(tt.x + tid, NTOK - 1)];

    // staging macros: H=0/1 selects 128-row half (source +H*512KB, dest quarter)
#define STA(o, m, b, H) { char* d_ = sh + (b) * 65536 + (H) * 16384 + ldsOff;        \
        load_lds16((const char*)Ab + (o) + (H) * 524288u + (m) * 128, d_);            \
        load_lds16((const char*)Ab + (o) + (H) * 524288u + (m) * 128 + 32768u, d_ + 1024); }
#define STB(o, m, b, H) { char* d_ = sh + (b) * 65536 + 32768 + (H) * 16384 + ldsOff; \
        load_lds16((const char*)Wb + (o) + (H) * 524288u + (m) * 128, d_);            \
        load_lds16((const char*)Wb + (o) + (H) * 524288u + (m) * 128 + 32768u, d_ + 1024); }

#define RDA(dst, mf0, b) { _Pragma("unroll") for (int m_ = 0; m_ < 4; ++m_) {        \
        const char* p_ = sh + (b) * 65536 + aRow + ((mf0) + m_) * 2048;              \
        dst[m_][0] = *(const bf16x8*)(p_ + s0);                                      \
        dst[m_][1] = *(const bf16x8*)(p_ + (s0 ^ 64)); } }
#define RDB(dst, nf0, b) { _Pragma("unroll") for (int n_ = 0; n_ < 2; ++n_) {        \
        const char* p_ = sh + (b) * 65536 + bRow + ((nf0) + n_) * 2048;              \
        dst[n_][0] = *(const bf16x8*)(p_ + s0);                                      \
        dst[n_][1] = *(const bf16x8*)(p_ + (s0 ^ 64)); } }

#define QUAD(RA, RB, MO, NO) { __builtin_amdgcn_s_setprio(1);                        \
    _Pragma("unroll") for (int m_ = 0; m_ < 4; ++m_)                                 \
    _Pragma("unroll") for (int n_ = 0; n_ < 2; ++n_) {                               \
        acc[(MO)+m_][(NO)+n_] = __builtin_amdgcn_mfma_f32_16x16x32_bf16(             \
            RA[m_][0], RB[n_][0], acc[(MO)+m_][(NO)+n_], 0, 0, 0);                   \
        acc[(MO)+m_][(NO)+n_] = __builtin_amdgcn_mfma_f32_16x16x32_bf16(             \
            RA[m_][1], RB[n_][1], acc[(MO)+m_][(NO)+n_], 0, 0, 0); }                 \
    __builtin_amdgcn_s_setprio(0); }

    bf16x8 ra0[4][2], ra1[4][2], rb0[2][2], rb1[2][2];
    f32x4 acc[8][4];

    // --- first-tile prologue: K0 full + K1 partial (B0,B1,A0) ---
    STA(aO, 0, 0, 0); STA(aO, 0, 0, 1); STB(bO, 0, 0, 0); STB(bO, 0, 0, 1);
    STB(bO, 1, 1, 0); STB(bO, 1, 1, 1); STA(aO, 1, 1, 0);

    for (;;) {
        // ===== tile loop top: everything staged for K0/K1 of current tile =====
        WVM(0);
        BARS();
        if (tid < 256) listLds[tid] = vvn;    // epilogue scatter list
        RDA(ra0, 0, 0); RDB(rb0, 0, 0);
#pragma unroll
        for (int i = 0; i < 8; ++i)
#pragma unroll
            for (int j = 0; j < 4; ++j) acc[i][j] = (f32x4){0.f, 0.f, 0.f, 0.f};

        // --- main loop: K-tiles 0..29 ---
        for (int j = 0; j < 30; ++j) {
            int b = j & 1, nb = b ^ 1;
            RDB(rb1, 2, b);
            STA(aO, j + 1, nb, 1);
            QUAD(ra0, rb0, 0, 0);
            BARS();
            RDA(ra1, 4, b);
            STB(bO, j + 2, b, 0);
            QUAD(ra0, rb1, 0, 2);
            BARS();
            STB(bO, j + 2, b, 1);
            QUAD(ra1, rb0, 4, 0);
            BARS();
            WVM(4);
            BARS();
            RDA(ra0, 0, nb);
            RDB(rb0, 0, nb);
            STA(aO, j + 2, b, 0);
            QUAD(ra1, rb1, 4, 2);
            BARS();
        }

        // --- tail K30 (buf0) ---
        RDB(rb1, 2, 0);
        STA(aO, 31, 1, 1);
        QUAD(ra0, rb0, 0, 0);
        BARS();
        RDA(ra1, 4, 0);
        QUAD(ra0, rb1, 0, 2);
        BARS();
        QUAD(ra1, rb0, 4, 0);
        BARS();
        WVM(0);
        BARS();

        // --- steal next sid (vmcnt==0 here, so full-drain sync is free) ---
        if (tid == 0) *shsid = atomicAdd(&ctrl[19], 1);
        WLG0();
        BARS();
        int sid2 = *shsid;
        int have2 = sid2 < total;
        int cnt2 = 0, cb2 = 0, vvn2 = 0;
        u32 aO2 = 0, bO2 = 0;
        if (have2) {
            int4 t2 = tileTable[sid2 >> 3];
            cnt2 = t2.y - t2.x;
            cb2 = (sid2 & 7) * BN + wn * 64 + (lane & 15);
            aO2 = (u32)(t2.x + srow) * 4096u + ksoB;
            bO2 = (u32)(t2.z * NOUT + (sid2 & 7) * BN + srow) * 4096u + ksoB;
            if (tid < 256) vvn2 = list[min(t2.x + tid, NTOK - 1)];
        }

        // --- tail K31 (buf1), next-tile K0 staged into freed buf0 ---
        RDA(ra0, 0, 1); RDB(rb0, 0, 1);
        QUAD(ra1, rb1, 4, 2);                 // K30's last quadrant
        if (have2) {
            STA(aO2, 0, 0, 0); STA(aO2, 0, 0, 1);
            STB(bO2, 0, 0, 0); STB(bO2, 0, 0, 1);
        }
        RDB(rb1, 2, 1);
        QUAD(ra0, rb0, 0, 0);
        RDA(ra1, 4, 1);
        QUAD(ra0, rb1, 0, 2);
        QUAD(ra1, rb0, 4, 0);
        QUAD(ra1, rb1, 4, 2);

        // --- epilogue: C/D col=lane&15, row=(lane>>4)*4+reg; token scatter ---
#pragma unroll
        for (int mf = 0; mf < 8; ++mf) {
            int r0 = wm * 128 + mf * 16 + ((lane >> 4) << 2);
#pragma unroll
            for (int rr = 0; rr < 4; ++rr) {
                int rl = r0 + rr;
                if (rl < cnt) {
                    float* orow = out + (size_t)listLds[rl] * NOUT + cb;
#pragma unroll
                    for (int nf = 0; nf < 4; ++nf) orow[nf * 16] = acc[mf][nf][rr];
                }
            }
        }
        if (!have2) return;

        // --- next-tile K1 partial into buf1 (after K31 reads consumed) ---
        STB(bO2, 1, 1, 0); STB(bO2, 1, 1, 1); STA(aO2, 1, 1, 0);

        // roll tile state
        cnt = cnt2; cb = cb2; aO = aO2; bO = bO2; vvn = vvn2;
    }
#undef STA
#undef STB
#undef RDA
#undef RDB
#undef QUAD
}

// Correct-but-slow fp32 fallback if ws_size is insufficient.
__global__ void fallback_k(const float* __restrict__ A, const int* __restrict__ assign,
                           const float* __restrict__ W, float* __restrict__ out) {
    long idx = (long)blockIdx.x * 256 + threadIdx.x;  // NTOK*NOUT
    int t = (int)(idx >> 11);
    int n = (int)(idx & (NOUT - 1));
    int e = assign[t];
    const float4* a = (const float4*)(A + (size_t)t * KIN);
    const float4* w = (const float4*)(W + ((size_t)e * NOUT + n) * KIN);
    float s = 0.f;
    for (int k = 0; k < KIN / 4; k++) {
        float4 x = a[k], y = w[k];
        s += x.x * y.x + x.y * y.y + x.z * y.z + x.w * y.w;
    }
    out[idx] = s;
}

extern "C" void kernel_launch(void* const* d_in, const int* in_sizes, int n_in,
                              void* d_out, int out_size, void* d_ws, size_t ws_size,
                              hipStream_t stream) {
    const float* A = (const float*)d_in[0];
    const int* assign = (const int*)d_in[1];
    const float* W = (const float*)d_in[2];
    float* out = (float*)d_out;

    const size_t Ab_bytes = (size_t)NTOK * KIN * 2;            // 134 MB bf16 A (gathered)
    const size_t Wb_bytes = (size_t)NEXP * NOUT * KIN * 2;     // 67 MB bf16 W
    const size_t list_bytes = (size_t)NTOK * 4;
    const size_t rank_bytes = (size_t)NTOK * 4;
    const size_t bb_bytes = (size_t)NBLK * NEXP * 4;
    const size_t ctrl_bytes = 256;
    const size_t tt_bytes = (size_t)MAXTILE * 16;
    const size_t need = Ab_bytes + Wb_bytes + list_bytes + rank_bytes +
                        bb_bytes + ctrl_bytes + tt_bytes;

    if (ws_size < need) {
        fallback_k<<<(NTOK * (long)NOUT) / 256, 256, 0, stream>>>(A, assign, W, out);
        return;
    }

    char* p = (char*)d_ws;
    u16* Ab = (u16*)p;                     p += Ab_bytes;
    u16* Wb = (u16*)p;                     p += Wb_bytes;
    int* list = (int*)p;                   p += list_bytes;
    int* rank = (int*)p;                   p += rank_bytes;
    int* blockBase = (int*)p;              p += bb_bytes;
    int* ctrl = (int*)p;                   p += ctrl_bytes;
    int4* tileTable = (int4*)p;

    static bool attr_done = false;
    if (!attr_done) {
        hipFuncSetAttribute((const void*)gemm_k,
                            hipFuncAttributeMaxDynamicSharedMemorySize, 132352);
        attr_done = true;
    }

    hipMemsetAsync(ctrl, 0, ctrl_bytes, stream);
    rank_k<<<NBLK, 256, 0, stream>>>(assign, ctrl, rank, blockBase);
    prefix_k<<<1, 256, 0, stream>>>(ctrl, tileTable);
    gather_k<<<NTOK / 8, 256, 0, stream>>>(A, assign, rank, blockBase, ctrl, Ab, list);
    conv_k<<<(NEXP * NOUT * (KIN / 8)) / 256, 256, 0, stream>>>(W, Wb);
    gemm_k<<<256, 512, 132352, stream>>>(Ab, Wb, list, tileTable, ctrl, out);
}